// Round 15
// baseline (603.634 us; speedup 1.0000x reference)
//
#include <hip/hip_runtime.h>
#include <math.h>

#define N_NODES 50000
#define N_EDGES 800000
#define N_QE    100000
#define D       128

// ---- workspace layout (bytes) ----
static const size_t O_CNT = 0;                        // int[N]
static const size_t O_OFF = 256u * 1024;              // int[N+1]
static const size_t O_CUR = 512u * 1024;              // int[N]
static const size_t O_BS  = 768u * 1024;              // int[256] block sums
static const size_t O_SRC = 1024u * 1024;             // int[E] (3.2 MB)
static const size_t O_A   = 8u << 20;                 // float[N*D] 25.6 MB
static const size_t O_B   = O_A + 25600000u;          // float[N*D] 25.6 MB

// ---- CSR build ----
__global__ void k_count(const int* __restrict__ dst, int* __restrict__ cnt) {
    int e = blockIdx.x * 256 + threadIdx.x;
    if (e < N_EDGES) atomicAdd(&cnt[dst[e]], 1);
}

__global__ __launch_bounds__(256)
void k_scan1(const int* __restrict__ cnt, int* __restrict__ off,
             int* __restrict__ bsum) {
    __shared__ int sh[256];
    const int t = threadIdx.x;
    const int i = blockIdx.x * 256 + t;
    int v = (i < N_NODES) ? cnt[i] : 0;
    sh[t] = v;
    __syncthreads();
    #pragma unroll
    for (int o = 1; o < 256; o <<= 1) {
        int u = (t >= o) ? sh[t - o] : 0;
        __syncthreads();
        sh[t] += u;
        __syncthreads();
    }
    if (i < N_NODES) off[i] = sh[t] - v;
    if (t == 255) bsum[blockIdx.x] = sh[255];
}

__global__ __launch_bounds__(256)
void k_scan2(int* __restrict__ bsum, int nblk) {
    __shared__ int sh[256];
    const int t = threadIdx.x;
    int v = (t < nblk) ? bsum[t] : 0;
    sh[t] = v;
    __syncthreads();
    #pragma unroll
    for (int o = 1; o < 256; o <<= 1) {
        int u = (t >= o) ? sh[t - o] : 0;
        __syncthreads();
        sh[t] += u;
        __syncthreads();
    }
    if (t < nblk) bsum[t] = sh[t] - v;
}

__global__ __launch_bounds__(256)
void k_scan3(int* __restrict__ off, const int* __restrict__ bsum,
             int* __restrict__ cur) {
    const int i = blockIdx.x * 256 + threadIdx.x;
    if (i < N_NODES) {
        int o = off[i] + bsum[blockIdx.x];
        off[i] = o;
        cur[i] = o;
    }
    if (i == 0) off[N_NODES] = N_EDGES;
}

__global__ void k_scatter(const int* __restrict__ src, const int* __restrict__ dst,
                          int* __restrict__ cur, int* __restrict__ srcs) {
    int e = blockIdx.x * 256 + threadIdx.x;
    if (e < N_EDGES) {
        int p = atomicAdd(&cur[dst[e]], 1);
        srcs[p] = src[e];
    }
}

// ---- GEMM: Y[rows x 128] = X[rows x 128] @ W[128 x 128], fp32 ----
// 512 threads / 64-row tile, 32-k chunks. In-place safe (X==Y).
__global__ __launch_bounds__(512)
void k_gemm(const float* __restrict__ X, const float* __restrict__ W,
            float* __restrict__ Y, int rows)
{
    __shared__ float xs[64][36];
    __shared__ float ws[32 * 128];
    const int tid = threadIdx.x;
    const int tx = tid & 31;
    const int ty = tid >> 5;
    const int row0 = blockIdx.x * 64;
    float acc[4][4] = {};

    for (int kc = 0; kc < 4; ++kc) {
        const int kb = kc * 32;
        __syncthreads();
        {
            int r = tid >> 3, kq = tid & 7;
            int gr = row0 + r; if (gr >= rows) gr = rows - 1;
            float4 v = *(const float4*)(X + (size_t)gr * D + kb + kq * 4);
            *(float4*)&xs[r][kq * 4] = v;
        }
        #pragma unroll
        for (int it = 0; it < 2; ++it) {
            int f = it * 512 + tid;
            int k = f >> 5, cq = f & 31;
            *(float4*)&ws[k * 128 + cq * 4] =
                *(const float4*)(W + (size_t)(kb + k) * D + cq * 4);
        }
        __syncthreads();

        #pragma unroll 2
        for (int k4 = 0; k4 < 32; k4 += 4) {
            float4 wv[4];
            #pragma unroll
            for (int kk = 0; kk < 4; ++kk)
                wv[kk] = *(const float4*)&ws[(k4 + kk) * 128 + tx * 4];
            #pragma unroll
            for (int i = 0; i < 4; ++i) {
                float4 xv = *(const float4*)&xs[ty * 4 + i][k4];
                float xk[4] = {xv.x, xv.y, xv.z, xv.w};
                #pragma unroll
                for (int kk = 0; kk < 4; ++kk) {
                    acc[i][0] = fmaf(xk[kk], wv[kk].x, acc[i][0]);
                    acc[i][1] = fmaf(xk[kk], wv[kk].y, acc[i][1]);
                    acc[i][2] = fmaf(xk[kk], wv[kk].z, acc[i][2]);
                    acc[i][3] = fmaf(xk[kk], wv[kk].w, acc[i][3]);
                }
            }
        }
    }

    #pragma unroll
    for (int i = 0; i < 4; ++i) {
        int gr = row0 + ty * 4 + i;
        if (gr < rows)
            *(float4*)(Y + (size_t)gr * D + tx * 4) =
                make_float4(acc[i][0], acc[i][1], acc[i][2], acc[i][3]);
    }
}

// ---- CSR aggregation (fp32): one node per HALF-WAVE (R13-verified) ----
template<bool RELU>
__global__ __launch_bounds__(256)
void k_agg(const float* __restrict__ Hin, const int* __restrict__ off,
           const int* __restrict__ srcs, const float* __restrict__ bias,
           float* __restrict__ Hout)
{
    const int tid  = threadIdx.x;
    const int lane = tid & 63;
    const int half = lane >> 5;
    const int q    = lane & 31;
    const int wv   = tid >> 6;                       // 0..3
    const int n    = blockIdx.x * 8 + wv * 2 + half; // node per half-wave
    const int j0 = off[n], j1 = off[n + 1];

    float4 acc = make_float4(0.f, 0.f, 0.f, 0.f);
    int j = j0;
    while (j < j1) {
        int cnt = j1 - j; if (cnt > 32) cnt = 32;
        int idx = (q < cnt) ? srcs[j + q] : 0;
        #pragma unroll 8
        for (int k = 0; k < cnt; ++k) {
            int s = __shfl(idx, half * 32 + k, 64);
            const float4 v = *(const float4*)(Hin + (size_t)s * D + q * 4);
            acc.x += v.x; acc.y += v.y; acc.z += v.z; acc.w += v.w;
        }
        j += cnt;
    }
    const float4 bb = *(const float4*)(bias + q * 4);
    float4 o = make_float4(acc.x + bb.x, acc.y + bb.y,
                           acc.z + bb.z, acc.w + bb.w);
    if (RELU) {
        o.x = fmaxf(o.x, 0.f); o.y = fmaxf(o.y, 0.f);
        o.z = fmaxf(o.z, 0.f); o.w = fmaxf(o.w, 0.f);
    }
    *(float4*)(Hout + (size_t)n * D + q * 4) = o;
}

// ---- fused link predictor v3: ratio-16 register blocking ----
// 256 threads, 128 edges/block. Thread (tx,tyg): tx=tid&15 owns cols
// tx*8..+7; tyg=tid>>4 owns rows tyg+16*i (i=0..7) -> acc[8][8].
// FMAs per b128 LDS read = 16 (vs 8 in R8) -> LDS-throughput model 62 us.
// xs stride 132: rows within a wave differ by 1 -> 16 distinct banks,
// conflict-free. ws col-swizzle c+((c>>5)<<2), stride 144 -> 2-way (free).
// LDS total 76.8 KB -> 2 blocks/CU (gather/GEMM overlap across blocks).
#define XS_S 132
#define WS_S 144
__global__ __launch_bounds__(256)
void k_pred(const float* __restrict__ emb, const int* __restrict__ te,
            const float* __restrict__ P1, const float* __restrict__ pb1,
            const float* __restrict__ P2, const float* __restrict__ pb2,
            const float* __restrict__ P3, const float* __restrict__ pb3,
            float* __restrict__ out)
{
    __shared__ float xs[128 * XS_S];   // 67.6 KB
    __shared__ float ws[16 * WS_S];    // 9.2 KB
    const int tid = threadIdx.x;       // 0..255
    const int tx  = tid & 15;          // cols tx*8 .. +7
    const int tyg = tid >> 4;          // 0..15; rows tyg + 16*i
    const int row0 = blockIdx.x * 128;

    // ---- stage z0 = emb[s]*emb[d] (4096 float4 slots / 256 threads)
    #pragma unroll 4
    for (int it = 0; it < 16; ++it) {
        int slot = it * 256 + tid;     // 0..4095
        int r = slot >> 5, c4 = slot & 31;
        int e = row0 + r; if (e >= N_QE) e = N_QE - 1;
        int2 ep = *(const int2*)(te + 2 * e);
        float4 a = *(const float4*)(emb + (size_t)ep.x * D + c4 * 4);
        float4 b = *(const float4*)(emb + (size_t)ep.y * D + c4 * 4);
        *(float4*)&xs[r * XS_S + c4 * 4] =
            make_float4(a.x * b.x, a.y * b.y, a.z * b.z, a.w * b.w);
    }

    const int cbase = tx * 8 + ((tx >> 2) << 2);   // swizzled ws col base
    float acc[8][8];

    #pragma unroll
    for (int layer = 0; layer < 2; ++layer) {
        const float* W = layer ? P2 : P1;
        const float* bb = layer ? pb2 : pb1;
        #pragma unroll
        for (int i = 0; i < 8; ++i)
            #pragma unroll
            for (int c = 0; c < 8; ++c) acc[i][c] = 0.f;

        for (int kc = 0; kc < 8; ++kc) {           // 16-k chunks
            const int kb = kc * 16;
            __syncthreads();   // prev chunk consumed / (kc=0) xs writes done
            #pragma unroll
            for (int it = 0; it < 2; ++it) {       // stage 512 float4 slots
                int f = it * 256 + tid;
                int k = f >> 5, cq = f & 31;
                int c = cq * 4;
                *(float4*)&ws[k * WS_S + c + ((c >> 5) << 2)] =
                    *(const float4*)(W + (size_t)(kb + k) * D + c);
            }
            __syncthreads();

            #pragma unroll
            for (int k4 = 0; k4 < 16; k4 += 4) {
                float4 wv[4][2];
                #pragma unroll
                for (int kk = 0; kk < 4; ++kk) {
                    wv[kk][0] = *(const float4*)&ws[(k4 + kk) * WS_S + cbase];
                    wv[kk][1] = *(const float4*)&ws[(k4 + kk) * WS_S + cbase + 4];
                }
                #pragma unroll
                for (int i = 0; i < 8; ++i) {
                    float4 xv = *(const float4*)&xs[(tyg + 16 * i) * XS_S + kb + k4];
                    float xk[4] = {xv.x, xv.y, xv.z, xv.w};
                    #pragma unroll
                    for (int kk = 0; kk < 4; ++kk) {
                        acc[i][0] = fmaf(xk[kk], wv[kk][0].x, acc[i][0]);
                        acc[i][1] = fmaf(xk[kk], wv[kk][0].y, acc[i][1]);
                        acc[i][2] = fmaf(xk[kk], wv[kk][0].z, acc[i][2]);
                        acc[i][3] = fmaf(xk[kk], wv[kk][0].w, acc[i][3]);
                        acc[i][4] = fmaf(xk[kk], wv[kk][1].x, acc[i][4]);
                        acc[i][5] = fmaf(xk[kk], wv[kk][1].y, acc[i][5]);
                        acc[i][6] = fmaf(xk[kk], wv[kk][1].z, acc[i][6]);
                        acc[i][7] = fmaf(xk[kk], wv[kk][1].w, acc[i][7]);
                    }
                }
            }
        }
        // bias + relu
        #pragma unroll
        for (int i = 0; i < 8; ++i)
            #pragma unroll
            for (int c = 0; c < 8; ++c)
                acc[i][c] = fmaxf(acc[i][c] + bb[tx * 8 + c], 0.f);
        if (layer == 0) {
            __syncthreads();          // all xs reads of layer 0 done
            #pragma unroll
            for (int i = 0; i < 8; ++i) {
                float* p = &xs[(tyg + 16 * i) * XS_S + tx * 8];
                *(float4*)p       = make_float4(acc[i][0], acc[i][1], acc[i][2], acc[i][3]);
                *(float4*)(p + 4) = make_float4(acc[i][4], acc[i][5], acc[i][6], acc[i][7]);
            }
        }
    }

    // ---- epilogue: v = h2 @ P3 + pb3 (2 cols), reduce over 16 tx lanes
    float p0[8], p1[8];
    #pragma unroll
    for (int i = 0; i < 8; ++i) { p0[i] = 0.f; p1[i] = 0.f; }
    #pragma unroll
    for (int c = 0; c < 8; ++c) {
        float2 p3 = *(const float2*)(P3 + (size_t)(tx * 8 + c) * 2);
        #pragma unroll
        for (int i = 0; i < 8; ++i) {
            p0[i] = fmaf(acc[i][c], p3.x, p0[i]);
            p1[i] = fmaf(acc[i][c], p3.y, p1[i]);
        }
    }
    #pragma unroll
    for (int i = 0; i < 8; ++i) {
        #pragma unroll
        for (int o = 1; o < 16; o <<= 1) {   // stays within 16-lane tx group
            p0[i] += __shfl_xor(p0[i], o, 64);
            p1[i] += __shfl_xor(p1[i], o, 64);
        }
    }
    if (tx == 0) {
        const float q0 = pb3[0], q1 = pb3[1];
        #pragma unroll
        for (int i = 0; i < 8; ++i) {
            int gr = row0 + tyg + 16 * i;
            if (gr < N_QE) {
                float v0 = p0[i] + q0, v1 = p1[i] + q1;
                float nrm = fmaxf(sqrtf(v0 * v0 + v1 * v1), 1e-12f);
                v0 /= nrm; v1 /= nrm;
                float m = fmaxf(v0, v1);
                float lse = m + logf(expf(v0 - m) + expf(v1 - m));
                out[gr * 2]     = v0 - lse;
                out[gr * 2 + 1] = v1 - lse;
            }
        }
    }
}

extern "C" void kernel_launch(void* const* d_in, const int* in_sizes, int n_in,
                              void* d_out, int out_size, void* d_ws, size_t ws_size,
                              hipStream_t stream)
{
    (void)in_sizes; (void)n_in; (void)out_size; (void)ws_size;
    const float* x   = (const float*)d_in[0];
    const int*   adj = (const int*)d_in[1];
    const int*   te  = (const int*)d_in[2];
    const float* W1  = (const float*)d_in[3];
    const float* b1  = (const float*)d_in[4];
    const float* W2  = (const float*)d_in[5];
    const float* b2  = (const float*)d_in[6];
    const float* W3  = (const float*)d_in[7];
    const float* b3  = (const float*)d_in[8];
    const float* P1  = (const float*)d_in[9];
    const float* pb1 = (const float*)d_in[10];
    const float* P2  = (const float*)d_in[11];
    const float* pb2 = (const float*)d_in[12];
    const float* P3  = (const float*)d_in[13];
    const float* pb3 = (const float*)d_in[14];
    float* out = (float*)d_out;

    char* ws = (char*)d_ws;
    int* cnt  = (int*)(ws + O_CNT);
    int* off  = (int*)(ws + O_OFF);
    int* cur  = (int*)(ws + O_CUR);
    int* bsum = (int*)(ws + O_BS);
    int* srcs = (int*)(ws + O_SRC);
    float* A  = (float*)(ws + O_A);
    float* B  = (float*)(ws + O_B);

    const int* esrc = adj;
    const int* edst = adj + N_EDGES;

    const int SBLK = (N_NODES + 255) / 256;   // 196

    // CSR build (dst-sorted src list), reused by all 3 layers
    hipMemsetAsync(cnt, 0, N_NODES * sizeof(int), stream);
    k_count<<<N_EDGES / 256, 256, 0, stream>>>(edst, cnt);
    k_scan1<<<SBLK, 256, 0, stream>>>(cnt, off, bsum);
    k_scan2<<<1, 256, 0, stream>>>(bsum, SBLK);
    k_scan3<<<SBLK, 256, 0, stream>>>(off, bsum, cur);
    k_scatter<<<N_EDGES / 256, 256, 0, stream>>>(esrc, edst, cur, srcs);

    const int gN = (N_NODES + 63) / 64;    // 782
    const int gP = (N_QE + 127) / 128;     // 782

    // GCN trunk (all fp32, R13 config)
    k_gemm<<<gN, 512, 0, stream>>>(x, W1, A, N_NODES);
    k_agg<true><<<N_NODES / 8, 256, 0, stream>>>(A, off, srcs, b1, B);
    k_gemm<<<gN, 512, 0, stream>>>(B, W2, B, N_NODES);
    k_agg<true><<<N_NODES / 8, 256, 0, stream>>>(B, off, srcs, b2, A);
    k_gemm<<<gN, 512, 0, stream>>>(A, W3, A, N_NODES);
    k_agg<false><<<N_NODES / 8, 256, 0, stream>>>(A, off, srcs, b3, B); // B = emb

    // fused link predictor v3 (256 threads, 128 edges/block, ratio 16)
    k_pred<<<gP, 256, 0, stream>>>(B, te, P1, pb1, P2, pb2, P3, pb3, out);
}